// Round 14
// baseline (592.583 us; speedup 1.0000x reference)
//
#include <hip/hip_runtime.h>
#include <hip/hip_bf16.h>

#define DD 256      // feature dim
#define NM 64       // memory slots
#define RPB 32      // rows per block (main kernel)
#define NTHR 256    // 4 waves

typedef unsigned long long u64;

// ---------------------------------------------------------------------------
// prep_tr: wt[d][o] = W[o][d] for Wq and Wk (read-coalesced, scatter-write)
// ---------------------------------------------------------------------------
__global__ __launch_bounds__(256) void prep_tr(
    const float* __restrict__ Wq,    // [DD][DD]
    const float* __restrict__ Wk,    // [DD][DD]
    float* __restrict__ wqt,         // out [DD][DD]
    float* __restrict__ wkt)         // out [DD][DD]
{
    const int o = blockIdx.x;    // source row
    const int d = threadIdx.x;   // source col (coalesced read)
    if (blockIdx.y == 0) wqt[d * DD + o] = Wq[o * DD + d];
    else                 wkt[d * DD + o] = Wk[o * DD + d];
}

// ---------------------------------------------------------------------------
// prep_kT: kT4[(o>>2)*(NM*4) + n*4 + (o&3)] = k[n][o]
//          k[n][o] = sum_d mem[n][d]*Wk[o][d]  (fp32, d-ascending single-acc)
//          bias[n] = fl32(max(log(imp*0.99^age), -10))
// ---------------------------------------------------------------------------
__global__ __launch_bounds__(256) void prep_kT(
    const float* __restrict__ mem,   // [NM][DD]
    const float* __restrict__ wkt,   // [DD][DD]  (WkT: wkt[d][o])
    const float* __restrict__ imp,   // [NM]
    const float* __restrict__ age,   // [NM]
    float* __restrict__ kT4,         // out [DD/4][NM][4]
    float* __restrict__ bias)        // out [NM]
{
    const int n = blockIdx.x;   // memory slot
    const int o = threadIdx.x;  // output feature
    const float* mrow = mem + n * DD;     // uniform
    float acc = 0.f;
    for (int d = 0; d < DD; ++d)
        acc = fmaf(mrow[d], wkt[d * DD + o], acc);   // coalesced in o
    kT4[(o >> 2) * (NM * 4) + n * 4 + (o & 3)] = acc;

    if (o == 0) {
        double eff = (double)imp[n] * pow(0.99, (double)age[n]);
        float b = (float)log(eff);
        if (!(b >= -10.0f)) b = -10.0f;   // catches -inf/NaN too
        bias[n] = b;
    }
}

// ---------------------------------------------------------------------------
// fused main: 32 rows/block, 256 threads (4 waves), 32 KB LDS.
// = R13's phase structure (LDS-staged query, zero in-loop s_loads for query,
//   rolling VMEM prefetch of wqt) on R10's co-scheduling shape (256 thr /
//   32 KB measured 42% occupancy = 4 blocks/CU; 512-thr/64KB blocks pin at
//   ~8 waves/CU in R7/R9/R13).
//  A: q = query @ Wq^T  (wave w: rows 8w..8w+7; lane l: o=4l..4l+3;
//     query via uniform ds_read broadcast; chains d-ascending, bit-identical)
//  B: s = q @ kT        (lanes 0..31 = rows; wave w owns n in [16w,16w+16)
//     -> kT addr WAVE-uniform s_load, K$-hot; chains o-ascending)
//  2: per-row top-k (wave w, lanes 0..7 -> rows 8w..8w+7)
//  3: attn + PV float4 (chains rank-ascending) — all bit-identical to R13.
// LDS alias: query-stage (32KB) -> q (swizzled) -> s/sel.
// ---------------------------------------------------------------------------
__global__ __launch_bounds__(NTHR, 2) void mb_fused(
    const float* __restrict__ query,   // [M][DD]
    const float* __restrict__ mem,     // [NM][DD]
    const float4* __restrict__ wqt4,   // [DD][NM]: wqt4[d*64+l] = WqT[d][4l..4l+3]
    const float4* __restrict__ kT44,   // [DD/4][NM]: kT44[og*64+n] = k[n][4og..4og+3]
    const float* __restrict__ bias,    // [NM]
    const int* __restrict__ topk_p,
    float* __restrict__ out_ret,       // [M][DD]
    float* __restrict__ out_attn,      // [M][NM]
    int M)
{
    __shared__ float lds[RPB * DD];          // 32 KB: query-stage -> q -> s/sel
    float* s_f   = lds;                      //   s[32][64] (+r col rotation)
    int*   sel_i = (int*)(lds + RPB * NM);   //   [32][16]
    float* sel_w = lds + RPB * NM + RPB * 16;

    const int t = threadIdx.x;
    const int l = t & 63;
    const int w = __builtin_amdgcn_readfirstlane((int)(t >> 6));  // 0..3
    const int row0 = blockIdx.x * RPB;
    const int k = *topk_p;

    // ================= Stage: query rows -> LDS (coalesced VMEM) ==========
    {
        const float4* q4g = reinterpret_cast<const float4*>(query);
#pragma unroll
        for (int i = 0; i < (RPB * DD / 4) / NTHR; ++i) {   // 8 iters
            const int idx = i * NTHR + t;                   // 0..2047
            const int r   = idx >> 6;
            const int c4  = idx & 63;
            int gr = row0 + r; if (gr > M - 1) gr = M - 1;
            *reinterpret_cast<float4*>(&lds[r * DD + c4 * 4]) =
                q4g[(size_t)gr * 64 + c4];
        }
    }
    __syncthreads();

    // ================= Phase A: q-GEMM =================
    // wave w rows 8w..8w+7; lane l owns o = 4l..4l+3. query via uniform
    // ds_read broadcast; wqt via 1-deep rolling VMEM prefetch.
    float a0[8], a1[8], a2[8], a3[8];          // a{c}[rr]: o = 4l + c
    {
#pragma unroll
        for (int rr = 0; rr < 8; ++rr) { a0[rr] = 0.f; a1[rr] = 0.f; a2[rr] = 0.f; a3[rr] = 0.f; }

        // preload wqt tile for d0 = 0
        float4 cw0 = wqt4[0 * NM + l];
        float4 cw1 = wqt4[1 * NM + l];
        float4 cw2 = wqt4[2 * NM + l];
        float4 cw3 = wqt4[3 * NM + l];

        const float* qbase = &lds[(w * 8) * DD];   // wave's 8 query rows

        for (int d0 = 0; d0 < DD; d0 += 4) {
            const int dn = (d0 + 4) & (DD - 1);    // wraps on last iter
            const float4 nw0 = wqt4[(dn + 0) * NM + l];
            const float4 nw1 = wqt4[(dn + 1) * NM + l];
            const float4 nw2 = wqt4[(dn + 2) * NM + l];
            const float4 nw3 = wqt4[(dn + 3) * NM + l];
#pragma unroll
            for (int rr = 0; rr < 8; ++rr) {
                const float4 qq = *reinterpret_cast<const float4*>(
                    qbase + rr * DD + d0);         // uniform ds_read_b128 (broadcast)
                float v0 = a0[rr], v1 = a1[rr], v2 = a2[rr], v3 = a3[rr];
                // d-ascending per chain (identical to R13)
                v0 = fmaf(qq.x, cw0.x, v0); v0 = fmaf(qq.y, cw1.x, v0);
                v0 = fmaf(qq.z, cw2.x, v0); v0 = fmaf(qq.w, cw3.x, v0);
                v1 = fmaf(qq.x, cw0.y, v1); v1 = fmaf(qq.y, cw1.y, v1);
                v1 = fmaf(qq.z, cw2.y, v1); v1 = fmaf(qq.w, cw3.y, v1);
                v2 = fmaf(qq.x, cw0.z, v2); v2 = fmaf(qq.y, cw1.z, v2);
                v2 = fmaf(qq.z, cw2.z, v2); v2 = fmaf(qq.w, cw3.z, v2);
                v3 = fmaf(qq.x, cw0.w, v3); v3 = fmaf(qq.y, cw1.w, v3);
                v3 = fmaf(qq.z, cw2.w, v3); v3 = fmaf(qq.w, cw3.w, v3);
                a0[rr] = v0; a1[rr] = v1; a2[rr] = v2; a3[rr] = v3;
            }
            cw0 = nw0; cw1 = nw1; cw2 = nw2; cw3 = nw3;
        }
    }
    __syncthreads();   // all query reads done -> LDS reusable for q

    // ---- write q into LDS (swizzled: row lr, o-slot p stored at p^lr)
#pragma unroll
    for (int rr = 0; rr < 8; ++rr) {
        const int lr = w * 8 + rr;        // 0..31
        float4 v; v.x = a0[rr]; v.y = a1[rr]; v.z = a2[rr]; v.w = a3[rr];
        *reinterpret_cast<float4*>(&lds[lr * DD + (((l ^ lr) & 63) << 2)]) = v;
    }
    __syncthreads();

    // ================= Phase B: scores (registers only) =================
    // lanes 0..31: lane = row; wave w owns n in [16w, 16w+16) -> kT uniform
    const int r_b = l & 31;
    const int nb  = w * 16;
    float sc[16];
    if (l < 32) {
#pragma unroll
        for (int j = 0; j < 16; ++j) sc[j] = 0.f;

        for (int og = 0; og < DD / 4; ++og) {
            const float4 q4 = *reinterpret_cast<const float4*>(
                &lds[r_b * DD + (((og ^ r_b) & 63) << 2)]);
            const float4* ktp = kT44 + og * NM + nb;      // WAVE-uniform -> s_load
#pragma unroll
            for (int j = 0; j < 16; ++j) {
                const float4 kt = ktp[j];
                float v = sc[j];
                v = fmaf(q4.x, kt.x, v);
                v = fmaf(q4.y, kt.y, v);
                v = fmaf(q4.z, kt.z, v);
                v = fmaf(q4.w, kt.w, v);
                sc[j] = v;
            }
        }
    }
    __syncthreads();    // all q reads done -> LDS reusable for s/sel

    // ---- write scores into aliased s_f[32][64] (col c stored at (c+row)&63)
    if (l < 32) {
#pragma unroll
        for (int j = 0; j < 16; ++j)
            s_f[r_b * NM + ((nb + j + r_b) & 63)] = sc[j] * 0.0625f + bias[nb + j];
    }
    __syncthreads();

    // ================= Phase 2: per-row top-k (wave w, lanes 0..7) =========
    if (l < 8) {
        const int r = w * 8 + l;              // 0..31
        float sv[NM];
#pragma unroll
        for (int n = 0; n < NM; ++n) sv[n] = s_f[r * NM + ((n + r) & 63)];

        if (k < NM) {
            const int kk = k < 16 ? k : 16;   // dataset: k = 8
            u64 taken = 0ull;
            float mmax = 0.f, Z = 0.f;
            for (int i = 0; i < kk; ++i) {
                float m = -1.0e30f;
                int idx = 0;
#pragma unroll
                for (int n = 0; n < NM; ++n) {
                    const bool avail  = ((taken >> n) & 1ull) == 0ull;
                    const bool better = avail && (sv[n] > m);  // strict >: lowest idx ties
                    m   = better ? sv[n] : m;
                    idx = better ? n : idx;
                }
                taken |= (1ull << idx);
                if (i == 0) mmax = m;
                const float wv = expf(m - mmax);
                Z += wv;
                sel_i[r * 16 + i] = idx;
                sel_w[r * 16 + i] = wv;       // raw; divided once Z final
            }
#pragma unroll
            for (int n = 0; n < NM; ++n) s_f[r * NM + ((n + r) & 63)] = 0.f;
            for (int i = 0; i < kk; ++i) {
                const float wz = sel_w[r * 16 + i] / Z;
                sel_w[r * 16 + i] = wz;
                s_f[r * NM + ((sel_i[r * 16 + i] + r) & 63)] = wz;
            }
        } else {
            // full-softmax fallback (top_k >= N)
            float m = -1.0e30f;
#pragma unroll
            for (int n = 0; n < NM; ++n) m = sv[n] > m ? sv[n] : m;
            float Z = 0.f;
#pragma unroll
            for (int n = 0; n < NM; ++n) Z += expf(sv[n] - m);
#pragma unroll
            for (int n = 0; n < NM; ++n) s_f[r * NM + ((n + r) & 63)] = expf(sv[n] - m) / Z;
        }
    }
    __syncthreads();

    // ================= Phase 3a: attn stores (coalesced) =================
#pragma unroll
    for (int it = 0; it < (RPB * NM) / NTHR; ++it) {   // 8 iters
        const int idx  = it * NTHR + t;
        const int r    = idx >> 6, n = idx & 63;       // r uniform per wave
        const int grow = row0 + r;
        if (grow < M) out_attn[(size_t)grow * NM + n] = s_f[r * NM + ((n + r) & 63)];
    }

    // ================= Phase 3b: retrieved (PV), float4 per lane ===========
    // wave w rows [8w, 8w+8); lane l owns d-quad l (d = 4l..4l+3)
    {
        const float4* mem4 = reinterpret_cast<const float4*>(mem);   // [NM][64]
        const int kk = k < 16 ? k : 16;
#pragma unroll 1
        for (int rr = 0; rr < 8; ++rr) {
            const int r    = w * 8 + rr;
            const int grow = row0 + r;
            if (grow >= M) continue;
            float4 acc; acc.x = 0.f; acc.y = 0.f; acc.z = 0.f; acc.w = 0.f;
            if (k < NM) {
                for (int i = 0; i < kk; ++i) {
                    const int   mi = sel_i[r * 16 + i];
                    const float wz = sel_w[r * 16 + i];
                    const float4 mv = mem4[mi * 64 + l];       // coalesced 1KB
                    acc.x = fmaf(wz, mv.x, acc.x);             // rank-ascending chain
                    acc.y = fmaf(wz, mv.y, acc.y);
                    acc.z = fmaf(wz, mv.z, acc.z);
                    acc.w = fmaf(wz, mv.w, acc.w);
                }
            } else {
                for (int n = 0; n < NM; ++n) {
                    const float wz = s_f[r * NM + ((n + r) & 63)];
                    const float4 mv = mem4[n * 64 + l];
                    acc.x = fmaf(wz, mv.x, acc.x);             // n-ascending chain
                    acc.y = fmaf(wz, mv.y, acc.y);
                    acc.z = fmaf(wz, mv.z, acc.z);
                    acc.w = fmaf(wz, mv.w, acc.w);
                }
            }
            *reinterpret_cast<float4*>(&out_ret[(size_t)grow * DD + 4 * l]) = acc;
        }
    }
}

// ---------------------------------------------------------------------------
extern "C" void kernel_launch(void* const* d_in, const int* in_sizes, int n_in,
                              void* d_out, int out_size, void* d_ws, size_t ws_size,
                              hipStream_t stream) {
    const float* query      = (const float*)d_in[0];
    const float* memory     = (const float*)d_in[1];
    const float* importance = (const float*)d_in[2];
    const float* age        = (const float*)d_in[3];
    const float* Wq         = (const float*)d_in[4];
    const float* Wk         = (const float*)d_in[5];
    const int*   topk       = (const int*)d_in[6];

    const int M = in_sizes[0] / DD;   // B*S = 131072

    float* kT4  = (float*)d_ws;                      // [DD/4][NM][4] = 64 KB
    float* bias = kT4 + (size_t)DD * NM;             // [NM]
    float* wqt  = bias + 64;                         // [DD][DD] = 256 KB (16B aligned)
    float* wkt  = wqt + (size_t)DD * DD;             // [DD][DD] = 256 KB

    hipLaunchKernelGGL(prep_tr, dim3(DD, 2), dim3(DD), 0, stream,
                       Wq, Wk, wqt, wkt);
    hipLaunchKernelGGL(prep_kT, dim3(NM), dim3(DD), 0, stream,
                       memory, wkt, importance, age, kT4, bias);

    float* out_ret  = (float*)d_out;
    float* out_attn = out_ret + (size_t)M * DD;

    hipLaunchKernelGGL(mb_fused, dim3((M + RPB - 1) / RPB), dim3(NTHR), 0, stream,
                       query, memory,
                       (const float4*)wqt, (const float4*)kT4,
                       bias, topk, out_ret, out_attn, M);
}

// Round 15
// 493.393 us; speedup vs baseline: 1.2010x; 1.2010x over previous
//
#include <hip/hip_runtime.h>
#include <hip/hip_bf16.h>

#define DD 256      // feature dim
#define NM 64       // memory slots
#define RPB 64      // rows per block (main kernel)
#define NTHR 512    // 8 waves

typedef unsigned long long u64;
typedef float v2f __attribute__((ext_vector_type(2)));

struct v2x2 { v2f lo, hi; };
static __device__ __forceinline__ v2x2 splitf4(float4 f) {
    union { float4 a; v2x2 b; } u; u.a = f; return u.b;
}

// pk: acc(pair) += splat(src0 half) * c(pair).  Bit-identical to two fmaf.
#define PK_FMA_SPLATLO(acc, q2, c2) \
    asm("v_pk_fma_f32 %0, %1, %2, %0 op_sel:[0,0,0] op_sel_hi:[0,1,1]" \
        : "+v"(acc) : "v"(q2), "v"(c2))
#define PK_FMA_SPLATHI(acc, q2, c2) \
    asm("v_pk_fma_f32 %0, %1, %2, %0 op_sel:[1,0,0] op_sel_hi:[1,1,1]" \
        : "+v"(acc) : "v"(q2), "v"(c2))
// same, but multiplier pair from SGPRs (kT via s_load; 1 SGPR read: legal)
#define PK_FMA_SPLATLO_S(acc, q2, c2) \
    asm("v_pk_fma_f32 %0, %1, %2, %0 op_sel:[0,0,0] op_sel_hi:[0,1,1]" \
        : "+v"(acc) : "v"(q2), "s"(c2))
#define PK_FMA_SPLATHI_S(acc, q2, c2) \
    asm("v_pk_fma_f32 %0, %1, %2, %0 op_sel:[1,0,0] op_sel_hi:[1,1,1]" \
        : "+v"(acc) : "v"(q2), "s"(c2))

// ---------------------------------------------------------------------------
// prep_tr: wt[d][o] = W[o][d] for Wq and Wk (read-coalesced, scatter-write)
// ---------------------------------------------------------------------------
__global__ __launch_bounds__(256) void prep_tr(
    const float* __restrict__ Wq,    // [DD][DD]
    const float* __restrict__ Wk,    // [DD][DD]
    float* __restrict__ wqt,         // out [DD][DD]
    float* __restrict__ wkt)         // out [DD][DD]
{
    const int o = blockIdx.x;    // source row
    const int d = threadIdx.x;   // source col (coalesced read)
    if (blockIdx.y == 0) wqt[d * DD + o] = Wq[o * DD + d];
    else                 wkt[d * DD + o] = Wk[o * DD + d];
}

// ---------------------------------------------------------------------------
// prep_kT: interleaved pair layout for packed-fp32 Phase B:
//   kT8[og*256 + (n>>1)*8 + (o&3)*2 + (n&1)] = k[n][o],  og = o>>2
//   (pairs (n even, n odd) adjacent per d-component)
//   k[n][o] = sum_d mem[n][d]*Wk[o][d]  (fp32, d-ascending single-acc)
//   bias[n] = fl32(max(log(imp*0.99^age), -10))
// ---------------------------------------------------------------------------
__global__ __launch_bounds__(256) void prep_kT(
    const float* __restrict__ mem,   // [NM][DD]
    const float* __restrict__ wkt,   // [DD][DD]  (WkT: wkt[d][o])
    const float* __restrict__ imp,   // [NM]
    const float* __restrict__ age,   // [NM]
    float* __restrict__ kT8,         // out, 64 KB
    float* __restrict__ bias)        // out [NM]
{
    const int n = blockIdx.x;   // memory slot
    const int o = threadIdx.x;  // output feature
    const float* mrow = mem + n * DD;     // uniform
    float acc = 0.f;
    for (int d = 0; d < DD; ++d)
        acc = fmaf(mrow[d], wkt[d * DD + o], acc);   // coalesced in o
    kT8[(o >> 2) * 256 + (n >> 1) * 8 + (o & 3) * 2 + (n & 1)] = acc;

    if (o == 0) {
        double eff = (double)imp[n] * pow(0.99, (double)age[n]);
        float b = (float)log(eff);
        if (!(b >= -10.0f)) b = -10.0f;   // catches -inf/NaN too
        bias[n] = b;
    }
}

// ---------------------------------------------------------------------------
// fused main: R13 structure (64 rows, 512 thr, 64 KB LDS, LDS-staged query)
// + v_pk_fma_f32 packed fp32 in Phases A and B (2 chains per instruction,
//   each half an independent IEEE fma -> chains bit-identical to R13)
// + top-k on wave 0 (one row per lane; was 8 waves x 8 masked lanes).
// ---------------------------------------------------------------------------
__global__ __launch_bounds__(NTHR, 2) void mb_fused(
    const float* __restrict__ query,   // [M][DD]
    const float* __restrict__ mem,     // [NM][DD]
    const float4* __restrict__ wqt4,   // [DD][NM]: wqt4[d*64+l] = WqT[d][4l..4l+3]
    const float* __restrict__ kT8,     // packed pair layout (see prep_kT)
    const float* __restrict__ bias,    // [NM]
    const int* __restrict__ topk_p,
    float* __restrict__ out_ret,       // [M][DD]
    float* __restrict__ out_attn,      // [M][NM]
    int M)
{
    __shared__ float lds[RPB * DD];          // 64 KB: query-stage -> q -> s/sel
    float* s_f   = lds;                      //   s[64][64] (+r col rotation)
    int*   sel_i = (int*)(lds + RPB * NM);   //   [64][16]
    float* sel_w = lds + RPB * NM + RPB * 16;

    const int t = threadIdx.x;
    const int l = t & 63;
    const int w = __builtin_amdgcn_readfirstlane((int)(t >> 6));  // 0..7
    const int row0 = blockIdx.x * RPB;
    const int k = *topk_p;

    // ================= Stage: query rows -> LDS (coalesced VMEM) ==========
    {
        const float4* q4g = reinterpret_cast<const float4*>(query);
#pragma unroll
        for (int i = 0; i < (RPB * DD / 4) / NTHR; ++i) {   // 8 iters
            const int idx = i * NTHR + t;                   // 0..4095
            const int r   = idx >> 6;
            const int c4  = idx & 63;
            int gr = row0 + r; if (gr > M - 1) gr = M - 1;
            *reinterpret_cast<float4*>(&lds[r * DD + c4 * 4]) =
                q4g[(size_t)gr * 64 + c4];
        }
    }
    __syncthreads();

    // ================= Phase A: q-GEMM (packed fp32) =================
    // wave w rows 8w..8w+7; lane l owns o = 4l..4l+3 as pairs
    // a01[rr] = (q[row][4l], q[row][4l+1]); a23[rr] = (4l+2, 4l+3)
    v2f a01[8], a23[8];
    {
#pragma unroll
        for (int rr = 0; rr < 8; ++rr) { a01[rr] = (v2f)(0.f); a23[rr] = (v2f)(0.f); }

        // preload wqt tile for d0 = 0
        float4 cw0 = wqt4[0 * NM + l];
        float4 cw1 = wqt4[1 * NM + l];
        float4 cw2 = wqt4[2 * NM + l];
        float4 cw3 = wqt4[3 * NM + l];

        const float* qbase = &lds[(w * 8) * DD];   // wave's 8 query rows

        for (int d0 = 0; d0 < DD; d0 += 4) {
            const int dn = (d0 + 4) & (DD - 1);    // wraps on last iter
            const float4 nw0 = wqt4[(dn + 0) * NM + l];
            const float4 nw1 = wqt4[(dn + 1) * NM + l];
            const float4 nw2 = wqt4[(dn + 2) * NM + l];
            const float4 nw3 = wqt4[(dn + 3) * NM + l];
            const v2x2 c0 = splitf4(cw0), c1 = splitf4(cw1);
            const v2x2 c2 = splitf4(cw2), c3 = splitf4(cw3);
#pragma unroll
            for (int rr = 0; rr < 8; ++rr) {
                const float4 qq = *reinterpret_cast<const float4*>(
                    qbase + rr * DD + d0);         // uniform ds_read_b128
                const v2x2 qh = splitf4(qq);       // (x,y), (z,w)
                // d-ascending per chain (bit-identical to R13):
                // d0  : qq.x * cw0.{x,y}/{z,w}
                PK_FMA_SPLATLO(a01[rr], qh.lo, c0.lo);
                PK_FMA_SPLATLO(a23[rr], qh.lo, c0.hi);
                // d0+1: qq.y * cw1
                PK_FMA_SPLATHI(a01[rr], qh.lo, c1.lo);
                PK_FMA_SPLATHI(a23[rr], qh.lo, c1.hi);
                // d0+2: qq.z * cw2
                PK_FMA_SPLATLO(a01[rr], qh.hi, c2.lo);
                PK_FMA_SPLATLO(a23[rr], qh.hi, c2.hi);
                // d0+3: qq.w * cw3
                PK_FMA_SPLATHI(a01[rr], qh.hi, c3.lo);
                PK_FMA_SPLATHI(a23[rr], qh.hi, c3.hi);
            }
            cw0 = nw0; cw1 = nw1; cw2 = nw2; cw3 = nw3;
        }
    }
    __syncthreads();   // all query reads done -> LDS reusable for q

    // ---- write q into LDS (swizzled: row lr, o-slot p stored at p^lr)
#pragma unroll
    for (int rr = 0; rr < 8; ++rr) {
        const int lr = w * 8 + rr;        // 0..63
        float4 v; v.x = a01[rr].x; v.y = a01[rr].y; v.z = a23[rr].x; v.w = a23[rr].y;
        *reinterpret_cast<float4*>(&lds[lr * DD + (((l ^ lr) & 63) << 2)]) = v;
    }
    __syncthreads();

    // ================= Phase B: scores (packed fp32, kT via s_load) ========
    // lane = row l; wave w owns n in [8w, 8w+8) as 4 pairs
    const int nb = w * 8;
    v2f p[4];
    {
#pragma unroll
        for (int j2 = 0; j2 < 4; ++j2) p[j2] = (v2f)(0.f);

        // wave-uniform base: v2f units: og*128 + (nb/2)*8 = og*128 + w*16
        const v2f* kt2base = reinterpret_cast<const v2f*>(kT8) + w * 16;

        for (int og = 0; og < DD / 4; ++og) {
            const float4 q4 = *reinterpret_cast<const float4*>(
                &lds[l * DD + (((og ^ l) & 63) << 2)]);       // 1 read / 64 rows
            const v2x2 qh = splitf4(q4);
            const v2f* kt2 = kt2base + og * 128;              // wave-uniform -> s_load
#pragma unroll
            for (int j2 = 0; j2 < 4; ++j2) {
                const v2f k0 = kt2[j2 * 4 + 0];   // (kA.d0, kB.d0)
                const v2f k1 = kt2[j2 * 4 + 1];
                const v2f k2 = kt2[j2 * 4 + 2];
                const v2f k3 = kt2[j2 * 4 + 3];
                // o-ascending per chain (bit-identical to R13)
                PK_FMA_SPLATLO_S(p[j2], qh.lo, k0);
                PK_FMA_SPLATHI_S(p[j2], qh.lo, k1);
                PK_FMA_SPLATLO_S(p[j2], qh.hi, k2);
                PK_FMA_SPLATHI_S(p[j2], qh.hi, k3);
            }
        }
    }
    __syncthreads();    // all q reads done -> LDS reusable for s/sel

    // ---- write scores into aliased s_f[64][64] (col c stored at (c+row)&63)
#pragma unroll
    for (int j2 = 0; j2 < 4; ++j2) {
        const int n0 = nb + 2 * j2;
        s_f[l * NM + ((n0     + l) & 63)] = p[j2].x * 0.0625f + bias[n0];
        s_f[l * NM + ((n0 + 1 + l) & 63)] = p[j2].y * 0.0625f + bias[n0 + 1];
    }
    __syncthreads();

    // ================= Phase 2: per-row top-k (wave 0, lane = row) =========
    if (w == 0) {
        const int r = l;                      // 0..63
        float sv[NM];
#pragma unroll
        for (int n = 0; n < NM; ++n) sv[n] = s_f[r * NM + ((n + r) & 63)];

        if (k < NM) {
            const int kk = k < 16 ? k : 16;   // dataset: k = 8
            u64 taken = 0ull;
            float mmax = 0.f, Z = 0.f;
            for (int i = 0; i < kk; ++i) {
                float m = -1.0e30f;
                int idx = 0;
#pragma unroll
                for (int n = 0; n < NM; ++n) {
                    const bool avail  = ((taken >> n) & 1ull) == 0ull;
                    const bool better = avail && (sv[n] > m);  // strict >: lowest idx ties
                    m   = better ? sv[n] : m;
                    idx = better ? n : idx;
                }
                taken |= (1ull << idx);
                if (i == 0) mmax = m;
                const float wv = expf(m - mmax);
                Z += wv;
                sel_i[r * 16 + i] = idx;
                sel_w[r * 16 + i] = wv;       // raw; divided once Z final
            }
#pragma unroll
            for (int n = 0; n < NM; ++n) s_f[r * NM + ((n + r) & 63)] = 0.f;
            for (int i = 0; i < kk; ++i) {
                const float wz = sel_w[r * 16 + i] / Z;
                sel_w[r * 16 + i] = wz;
                s_f[r * NM + ((sel_i[r * 16 + i] + r) & 63)] = wz;
            }
        } else {
            // full-softmax fallback (top_k >= N)
            float m = -1.0e30f;
#pragma unroll
            for (int n = 0; n < NM; ++n) m = sv[n] > m ? sv[n] : m;
            float Z = 0.f;
#pragma unroll
            for (int n = 0; n < NM; ++n) Z += expf(sv[n] - m);
#pragma unroll
            for (int n = 0; n < NM; ++n) s_f[r * NM + ((n + r) & 63)] = expf(sv[n] - m) / Z;
        }
    }
    __syncthreads();

    // ================= Phase 3a: attn stores (coalesced) =================
#pragma unroll
    for (int it = 0; it < (RPB * NM) / NTHR; ++it) {   // 8 iters
        const int idx  = it * NTHR + t;
        const int r    = idx >> 6, n = idx & 63;       // r uniform per wave
        const int grow = row0 + r;
        if (grow < M) out_attn[(size_t)grow * NM + n] = s_f[r * NM + ((n + r) & 63)];
    }

    // ================= Phase 3b: retrieved (PV), float4 per lane ===========
    // wave w rows [8w, 8w+8); lane l owns d-quad l (d = 4l..4l+3)
    {
        const float4* mem4 = reinterpret_cast<const float4*>(mem);   // [NM][64]
        const int kk = k < 16 ? k : 16;
#pragma unroll 1
        for (int rr = 0; rr < 8; ++rr) {
            const int r    = w * 8 + rr;
            const int grow = row0 + r;
            if (grow >= M) continue;
            float4 acc; acc.x = 0.f; acc.y = 0.f; acc.z = 0.f; acc.w = 0.f;
            if (k < NM) {
                for (int i = 0; i < kk; ++i) {
                    const int   mi = sel_i[r * 16 + i];
                    const float wz = sel_w[r * 16 + i];
                    const float4 mv = mem4[mi * 64 + l];       // coalesced 1KB
                    acc.x = fmaf(wz, mv.x, acc.x);             // rank-ascending chain
                    acc.y = fmaf(wz, mv.y, acc.y);
                    acc.z = fmaf(wz, mv.z, acc.z);
                    acc.w = fmaf(wz, mv.w, acc.w);
                }
            } else {
                for (int n = 0; n < NM; ++n) {
                    const float wz = s_f[r * NM + ((n + r) & 63)];
                    const float4 mv = mem4[n * 64 + l];
                    acc.x = fmaf(wz, mv.x, acc.x);             // n-ascending chain
                    acc.y = fmaf(wz, mv.y, acc.y);
                    acc.z = fmaf(wz, mv.z, acc.z);
                    acc.w = fmaf(wz, mv.w, acc.w);
                }
            }
            *reinterpret_cast<float4*>(&out_ret[(size_t)grow * DD + 4 * l]) = acc;
        }
    }
}

// ---------------------------------------------------------------------------
extern "C" void kernel_launch(void* const* d_in, const int* in_sizes, int n_in,
                              void* d_out, int out_size, void* d_ws, size_t ws_size,
                              hipStream_t stream) {
    const float* query      = (const float*)d_in[0];
    const float* memory     = (const float*)d_in[1];
    const float* importance = (const float*)d_in[2];
    const float* age        = (const float*)d_in[3];
    const float* Wq         = (const float*)d_in[4];
    const float* Wk         = (const float*)d_in[5];
    const int*   topk       = (const int*)d_in[6];

    const int M = in_sizes[0] / DD;   // B*S = 131072

    float* kT8  = (float*)d_ws;                      // 64 KB packed pair layout
    float* bias = kT8 + (size_t)DD * NM;             // [NM]
    float* wqt  = bias + 64;                         // [DD][DD] = 256 KB (16B aligned)
    float* wkt  = wqt + (size_t)DD * DD;             // [DD][DD] = 256 KB

    hipLaunchKernelGGL(prep_tr, dim3(DD, 2), dim3(DD), 0, stream,
                       Wq, Wk, wqt, wkt);
    hipLaunchKernelGGL(prep_kT, dim3(NM), dim3(DD), 0, stream,
                       memory, wkt, importance, age, kT8, bias);

    float* out_ret  = (float*)d_out;
    float* out_attn = out_ret + (size_t)M * DD;

    hipLaunchKernelGGL(mb_fused, dim3((M + RPB - 1) / RPB), dim3(NTHR), 0, stream,
                       query, memory,
                       (const float4*)wqt, kT8,
                       bias, topk, out_ret, out_attn, M);
}

// Round 16
// 415.303 us; speedup vs baseline: 1.4269x; 1.1880x over previous
//
#include <hip/hip_runtime.h>
#include <hip/hip_bf16.h>

#define DD 256      // feature dim
#define NM 64       // memory slots

typedef unsigned long long u64;
typedef float v2f __attribute__((ext_vector_type(2)));

struct v2x2 { v2f lo, hi; };
static __device__ __forceinline__ v2x2 splitf4(float4 f) {
    union { float4 a; v2x2 b; } u; u.a = f; return u.b;
}

// pk: acc(pair) += splat(src0 half) * c(pair).  Bit-identical to two fmaf.
#define PK_FMA_SPLATLO(acc, q2, c2) \
    asm("v_pk_fma_f32 %0, %1, %2, %0 op_sel:[0,0,0] op_sel_hi:[0,1,1]" \
        : "+v"(acc) : "v"(q2), "v"(c2))
#define PK_FMA_SPLATHI(acc, q2, c2) \
    asm("v_pk_fma_f32 %0, %1, %2, %0 op_sel:[1,0,0] op_sel_hi:[1,1,1]" \
        : "+v"(acc) : "v"(q2), "v"(c2))
// multiplier pair from SGPRs (kT via s_load; 1 SGPR read: legal)
#define PK_FMA_SPLATLO_S(acc, q2, c2) \
    asm("v_pk_fma_f32 %0, %1, %2, %0 op_sel:[0,0,0] op_sel_hi:[0,1,1]" \
        : "+v"(acc) : "v"(q2), "s"(c2))
#define PK_FMA_SPLATHI_S(acc, q2, c2) \
    asm("v_pk_fma_f32 %0, %1, %2, %0 op_sel:[1,0,0] op_sel_hi:[1,1,1]" \
        : "+v"(acc) : "v"(q2), "s"(c2))

// ---------------------------------------------------------------------------
// prep_tr: wt[d][o] = W[o][d] for Wq and Wk
// ---------------------------------------------------------------------------
__global__ __launch_bounds__(256) void prep_tr(
    const float* __restrict__ Wq, const float* __restrict__ Wk,
    float* __restrict__ wqt, float* __restrict__ wkt)
{
    const int o = blockIdx.x;
    const int d = threadIdx.x;
    if (blockIdx.y == 0) wqt[d * DD + o] = Wq[o * DD + d];
    else                 wkt[d * DD + o] = Wk[o * DD + d];
}

// ---------------------------------------------------------------------------
// prep_kT: interleaved pair layout for packed-fp32 scores:
//   kT8[og*256 + (n>>1)*8 + (o&3)*2 + (n&1)] = k[n][o],  og = o>>2
//   k[n][o] = sum_d mem[n][d]*Wk[o][d]  (fp32, d-ascending single-acc)
//   bias[n] = fl32(max(log(imp*0.99^age), -10))
// ---------------------------------------------------------------------------
__global__ __launch_bounds__(256) void prep_kT(
    const float* __restrict__ mem, const float* __restrict__ wkt,
    const float* __restrict__ imp, const float* __restrict__ age,
    float* __restrict__ kT8, float* __restrict__ bias)
{
    const int n = blockIdx.x;
    const int o = threadIdx.x;
    const float* mrow = mem + n * DD;
    float acc = 0.f;
    for (int d = 0; d < DD; ++d)
        acc = fmaf(mrow[d], wkt[d * DD + o], acc);
    kT8[(o >> 2) * 256 + (n >> 1) * 8 + (o & 3) * 2 + (n & 1)] = acc;

    if (o == 0) {
        double eff = (double)imp[n] * pow(0.99, (double)age[n]);
        float b = (float)log(eff);
        if (!(b >= -10.0f)) b = -10.0f;
        bias[n] = b;
    }
}

// ---------------------------------------------------------------------------
// qgemm: q = query @ Wq^T, written to qout (= out_ret region, reused as
// scratch; mb_fin later overwrites it row-block-locally with retrieved).
// 32 rows/block, 256 thr (4 waves), 32 KB LDS, 1 barrier. Chains: per (row,o)
// d-ascending single-acc fma — bit-identical to R15 Phase A (packed pairs).
// ---------------------------------------------------------------------------
__global__ __launch_bounds__(256, 2) void qgemm(
    const float* __restrict__ query,   // [M][DD]
    const float4* __restrict__ wqt4,   // [DD][NM]: wqt4[d*64+l] = WqT[d][4l..4l+3]
    float* __restrict__ qout,          // [M][DD]
    int M)
{
    __shared__ float lds[32 * DD];     // 32 KB staged query rows
    const int t = threadIdx.x;
    const int l = t & 63;
    const int w = __builtin_amdgcn_readfirstlane((int)(t >> 6));  // 0..3
    const int row0 = blockIdx.x * 32;

    // stage 32 query rows (coalesced)
    {
        const float4* q4g = reinterpret_cast<const float4*>(query);
#pragma unroll
        for (int i = 0; i < 8; ++i) {
            const int idx = i * 256 + t;       // 0..2047
            const int r = idx >> 6, c4 = idx & 63;
            int gr = row0 + r; if (gr > M - 1) gr = M - 1;
            *reinterpret_cast<float4*>(&lds[r * DD + c4 * 4]) =
                q4g[(size_t)gr * 64 + c4];
        }
    }
    __syncthreads();

    // wave w rows 8w..8w+7; lane l owns o = 4l..4l+3 as pairs
    v2f a01[8], a23[8];
#pragma unroll
    for (int rr = 0; rr < 8; ++rr) { a01[rr] = (v2f)(0.f); a23[rr] = (v2f)(0.f); }

    {
        float4 cw0 = wqt4[0 * NM + l];
        float4 cw1 = wqt4[1 * NM + l];
        float4 cw2 = wqt4[2 * NM + l];
        float4 cw3 = wqt4[3 * NM + l];

        const float* qbase = &lds[(w * 8) * DD];

        for (int d0 = 0; d0 < DD; d0 += 4) {
            const int dn = (d0 + 4) & (DD - 1);
            const float4 nw0 = wqt4[(dn + 0) * NM + l];
            const float4 nw1 = wqt4[(dn + 1) * NM + l];
            const float4 nw2 = wqt4[(dn + 2) * NM + l];
            const float4 nw3 = wqt4[(dn + 3) * NM + l];
            const v2x2 c0 = splitf4(cw0), c1 = splitf4(cw1);
            const v2x2 c2 = splitf4(cw2), c3 = splitf4(cw3);
#pragma unroll
            for (int rr = 0; rr < 8; ++rr) {
                const float4 qq = *reinterpret_cast<const float4*>(
                    qbase + rr * DD + d0);     // uniform ds_read_b128
                const v2x2 qh = splitf4(qq);
                // d-ascending per chain (bit-identical to R15)
                PK_FMA_SPLATLO(a01[rr], qh.lo, c0.lo);
                PK_FMA_SPLATLO(a23[rr], qh.lo, c0.hi);
                PK_FMA_SPLATHI(a01[rr], qh.lo, c1.lo);
                PK_FMA_SPLATHI(a23[rr], qh.lo, c1.hi);
                PK_FMA_SPLATLO(a01[rr], qh.hi, c2.lo);
                PK_FMA_SPLATLO(a23[rr], qh.hi, c2.hi);
                PK_FMA_SPLATHI(a01[rr], qh.hi, c3.lo);
                PK_FMA_SPLATHI(a23[rr], qh.hi, c3.hi);
            }
            cw0 = nw0; cw1 = nw1; cw2 = nw2; cw3 = nw3;
        }
    }

    // store q rows (coalesced: 64 lanes x 16B = 1KB per row)
#pragma unroll
    for (int rr = 0; rr < 8; ++rr) {
        const int grow = row0 + w * 8 + rr;
        if (grow < M) {
            float4 v; v.x = a01[rr].x; v.y = a01[rr].y; v.z = a23[rr].x; v.w = a23[rr].y;
            *reinterpret_cast<float4*>(&qout[(size_t)grow * DD + 4 * l]) = v;
        }
    }
}

// ---------------------------------------------------------------------------
// mb_fin: scores -> top-k -> softmax -> attn + retrieved.
// 64 rows/block, 256 thr (4 waves), 64 KB LDS.
// Reads q from qin (= out_ret), stages block's OWN rows to LDS, and at the
// end overwrites those same rows with retrieved — block-local RAW, no hazard.
// Chains o-ascending (scores), rank-ascending (PV) — bit-identical to R15.
// ---------------------------------------------------------------------------
__global__ __launch_bounds__(256, 2) void mb_fin(
    const float* __restrict__ qin,     // [M][DD] (aliases out_ret)
    const float* __restrict__ mem,     // [NM][DD]
    const float* __restrict__ kT8,     // packed pair layout
    const float* __restrict__ bias,    // [NM]
    const int* __restrict__ topk_p,
    float* __restrict__ out_ret,       // [M][DD] (same buffer as qin)
    float* __restrict__ out_attn,      // [M][NM]
    int M)
{
    __shared__ float lds[64 * DD];           // 64 KB: q-stage -> s/sel
    float* s_f   = lds;                      //   s[64][64] (+r col rotation)
    int*   sel_i = (int*)(lds + 64 * NM);    //   [64][16]
    float* sel_w = lds + 64 * NM + 64 * 16;

    const int t = threadIdx.x;
    const int l = t & 63;
    const int w = __builtin_amdgcn_readfirstlane((int)(t >> 6));  // 0..3
    const int row0 = blockIdx.x * 64;
    const int k = *topk_p;

    // stage 64 q rows (coalesced read, swizzled write: slot c4 -> c4^r)
    {
        const float4* q4g = reinterpret_cast<const float4*>(qin);
#pragma unroll
        for (int i = 0; i < 16; ++i) {
            const int idx = i * 256 + t;       // 0..4095
            const int r = idx >> 6, c4 = idx & 63;
            int gr = row0 + r; if (gr > M - 1) gr = M - 1;
            *reinterpret_cast<float4*>(&lds[r * DD + ((c4 ^ r) & 63) * 4]) =
                q4g[(size_t)gr * 64 + c4];
        }
    }
    __syncthreads();

    // ---- scores: lane = row l; wave w owns n in [16w,16w+16) as 8 pairs
    const int nb = w * 16;
    v2f p[8];
    {
#pragma unroll
        for (int j2 = 0; j2 < 8; ++j2) p[j2] = (v2f)(0.f);

        // v2f units: og*128 + (nb>>1)*4 = og*128 + w*32  (wave-uniform)
        const v2f* kt2base = reinterpret_cast<const v2f*>(kT8) + w * 32;

        for (int og = 0; og < DD / 4; ++og) {
            const float4 q4 = *reinterpret_cast<const float4*>(
                &lds[l * DD + (((og ^ l) & 63) << 2)]);
            const v2x2 qh = splitf4(q4);
            const v2f* kt2 = kt2base + og * 128;            // wave-uniform -> s_load
#pragma unroll
            for (int j2 = 0; j2 < 8; ++j2) {
                const v2f k0 = kt2[j2 * 4 + 0];
                const v2f k1 = kt2[j2 * 4 + 1];
                const v2f k2 = kt2[j2 * 4 + 2];
                const v2f k3 = kt2[j2 * 4 + 3];
                // o-ascending per chain (bit-identical to R15)
                PK_FMA_SPLATLO_S(p[j2], qh.lo, k0);
                PK_FMA_SPLATHI_S(p[j2], qh.lo, k1);
                PK_FMA_SPLATLO_S(p[j2], qh.hi, k2);
                PK_FMA_SPLATHI_S(p[j2], qh.hi, k3);
            }
        }
    }
    __syncthreads();    // all q reads done -> LDS reusable for s/sel

    // ---- write scores into aliased s_f[64][64] (col c stored at (c+row)&63)
#pragma unroll
    for (int j2 = 0; j2 < 8; ++j2) {
        const int n0 = nb + 2 * j2;
        s_f[l * NM + ((n0     + l) & 63)] = p[j2].x * 0.0625f + bias[n0];
        s_f[l * NM + ((n0 + 1 + l) & 63)] = p[j2].y * 0.0625f + bias[n0 + 1];
    }
    __syncthreads();

    // ---- per-row top-k (wave 0, lane = row)
    if (w == 0) {
        const int r = l;                      // 0..63
        float sv[NM];
#pragma unroll
        for (int n = 0; n < NM; ++n) sv[n] = s_f[r * NM + ((n + r) & 63)];

        if (k < NM) {
            const int kk = k < 16 ? k : 16;   // dataset: k = 8
            u64 taken = 0ull;
            float mmax = 0.f, Z = 0.f;
            for (int i = 0; i < kk; ++i) {
                float m = -1.0e30f;
                int idx = 0;
#pragma unroll
                for (int n = 0; n < NM; ++n) {
                    const bool avail  = ((taken >> n) & 1ull) == 0ull;
                    const bool better = avail && (sv[n] > m);  // strict >: lowest idx ties
                    m   = better ? sv[n] : m;
                    idx = better ? n : idx;
                }
                taken |= (1ull << idx);
                if (i == 0) mmax = m;
                const float wv = expf(m - mmax);
                Z += wv;
                sel_i[r * 16 + i] = idx;
                sel_w[r * 16 + i] = wv;
            }
#pragma unroll
            for (int n = 0; n < NM; ++n) s_f[r * NM + ((n + r) & 63)] = 0.f;
            for (int i = 0; i < kk; ++i) {
                const float wz = sel_w[r * 16 + i] / Z;
                sel_w[r * 16 + i] = wz;
                s_f[r * NM + ((sel_i[r * 16 + i] + r) & 63)] = wz;
            }
        } else {
            float m = -1.0e30f;
#pragma unroll
            for (int n = 0; n < NM; ++n) m = sv[n] > m ? sv[n] : m;
            float Z = 0.f;
#pragma unroll
            for (int n = 0; n < NM; ++n) Z += expf(sv[n] - m);
#pragma unroll
            for (int n = 0; n < NM; ++n) s_f[r * NM + ((n + r) & 63)] = expf(sv[n] - m) / Z;
        }
    }
    __syncthreads();

    // ---- attn stores (coalesced)
#pragma unroll
    for (int it = 0; it < 16; ++it) {
        const int idx  = it * 256 + t;
        const int r    = idx >> 6, n = idx & 63;       // r uniform per wave
        const int grow = row0 + r;
        if (grow < M) out_attn[(size_t)grow * NM + n] = s_f[r * NM + ((n + r) & 63)];
    }

    // ---- retrieved (PV): wave w rows [16w,16w+16); lane l = d-quad
    {
        const float4* mem4 = reinterpret_cast<const float4*>(mem);   // [NM][64]
        const int kk = k < 16 ? k : 16;
#pragma unroll 1
        for (int rr = 0; rr < 16; ++rr) {
            const int r    = w * 16 + rr;
            const int grow = row0 + r;
            if (grow >= M) continue;
            float4 acc; acc.x = 0.f; acc.y = 0.f; acc.z = 0.f; acc.w = 0.f;
            if (k < NM) {
                for (int i = 0; i < kk; ++i) {
                    const int   mi = sel_i[r * 16 + i];
                    const float wz = sel_w[r * 16 + i];
                    const float4 mv = mem4[mi * 64 + l];
                    acc.x = fmaf(wz, mv.x, acc.x);             // rank-ascending chain
                    acc.y = fmaf(wz, mv.y, acc.y);
                    acc.z = fmaf(wz, mv.z, acc.z);
                    acc.w = fmaf(wz, mv.w, acc.w);
                }
            } else {
                for (int n = 0; n < NM; ++n) {
                    const float wz = s_f[r * NM + ((n + r) & 63)];
                    const float4 mv = mem4[n * 64 + l];
                    acc.x = fmaf(wz, mv.x, acc.x);             // n-ascending chain
                    acc.y = fmaf(wz, mv.y, acc.y);
                    acc.z = fmaf(wz, mv.z, acc.z);
                    acc.w = fmaf(wz, mv.w, acc.w);
                }
            }
            *reinterpret_cast<float4*>(&out_ret[(size_t)grow * DD + 4 * l]) = acc;
        }
    }
}

// ---------------------------------------------------------------------------
extern "C" void kernel_launch(void* const* d_in, const int* in_sizes, int n_in,
                              void* d_out, int out_size, void* d_ws, size_t ws_size,
                              hipStream_t stream) {
    const float* query      = (const float*)d_in[0];
    const float* memory     = (const float*)d_in[1];
    const float* importance = (const float*)d_in[2];
    const float* age        = (const float*)d_in[3];
    const float* Wq         = (const float*)d_in[4];
    const float* Wk         = (const float*)d_in[5];
    const int*   topk       = (const int*)d_in[6];

    const int M = in_sizes[0] / DD;   // B*S = 131072

    float* kT8  = (float*)d_ws;                      // 64 KB packed pair layout
    float* bias = kT8 + (size_t)DD * NM;             // [NM]
    float* wqt  = bias + 64;                         // [DD][DD] = 256 KB
    float* wkt  = wqt + (size_t)DD * DD;             // [DD][DD] = 256 KB

    hipLaunchKernelGGL(prep_tr, dim3(DD, 2), dim3(DD), 0, stream,
                       Wq, Wk, wqt, wkt);
    hipLaunchKernelGGL(prep_kT, dim3(NM), dim3(DD), 0, stream,
                       memory, wkt, importance, age, kT8, bias);

    float* out_ret  = (float*)d_out;
    float* out_attn = out_ret + (size_t)M * DD;

    // q staged through out_ret (134 MB, exactly M*DD floats); mb_fin
    // reads its own rows before overwriting them with retrieved.
    hipLaunchKernelGGL(qgemm, dim3((M + 31) / 32), dim3(256), 0, stream,
                       query, (const float4*)wqt, out_ret, M);
    hipLaunchKernelGGL(mb_fin, dim3((M + 63) / 64), dim3(256), 0, stream,
                       out_ret, memory, kT8, bias, topk, out_ret, out_attn, M);
}